// Round 1
// baseline (1445.905 us; speedup 1.0000x reference)
//
#include <hip/hip_runtime.h>
#include <hip/hip_bf16.h>

#define N_NODES 100000
#define N_EDGES 1600000
#define IN_DIM  128
#define HID     64

// ---------------------------------------------------------------------------
// Kernel 1: h0 = relu(x @ Wi + bi)   (100000x128 @ 128x64)
// One wave per row; Wi staged in LDS; lane j computes output column j.
// ---------------------------------------------------------------------------
__global__ void gemm_in_kernel(const float* __restrict__ x,
                               const float* __restrict__ Wi,
                               const float* __restrict__ bi,
                               float* __restrict__ h0) {
    __shared__ float sW[IN_DIM * HID];  // 32 KB
    for (int i = threadIdx.x; i < IN_DIM * HID; i += blockDim.x) sW[i] = Wi[i];
    __syncthreads();

    const int lane = threadIdx.x & 63;
    const int wave = threadIdx.x >> 6;
    const int row  = blockIdx.x * (blockDim.x >> 6) + wave;
    if (row >= N_NODES) return;

    const float4* xr4 = (const float4*)(x + (size_t)row * IN_DIM);
    float acc = bi[lane];
    #pragma unroll
    for (int k4 = 0; k4 < IN_DIM / 4; ++k4) {
        float4 xv = xr4[k4];  // wave-uniform broadcast load, 16B
        acc += xv.x * sW[(4 * k4 + 0) * HID + lane];
        acc += xv.y * sW[(4 * k4 + 1) * HID + lane];
        acc += xv.z * sW[(4 * k4 + 2) * HID + lane];
        acc += xv.w * sW[(4 * k4 + 3) * HID + lane];
    }
    h0[(size_t)row * HID + lane] = fmaxf(acc, 0.0f);
}

// ---------------------------------------------------------------------------
// CSR build: histogram by tgt -> exclusive scan -> fill (src, weight) slots
// ---------------------------------------------------------------------------
__global__ void hist_kernel(const int* __restrict__ tgt, int* __restrict__ counts) {
    int e = blockIdx.x * blockDim.x + threadIdx.x;
    if (e < N_EDGES) atomicAdd(&counts[tgt[e]], 1);
}

__global__ void scan_kernel(const int* __restrict__ counts,
                            int* __restrict__ offs,
                            int* __restrict__ cursor) {
    // Single block, 1024 threads. Chunked sequential + Hillis-Steele over partials.
    __shared__ int partial[1024];
    const int T = 1024;
    const int tid = threadIdx.x;
    const int chunk = (N_NODES + T - 1) / T;  // 98
    const int start = tid * chunk;
    const int end   = min(start + chunk, N_NODES);

    int sum = 0;
    for (int i = start; i < end; ++i) sum += counts[i];
    partial[tid] = sum;
    __syncthreads();

    // inclusive scan of partial[]
    for (int off = 1; off < T; off <<= 1) {
        int v = (tid >= off) ? partial[tid - off] : 0;
        __syncthreads();
        partial[tid] += v;
        __syncthreads();
    }

    int run = partial[tid] - sum;  // exclusive base for this chunk
    for (int i = start; i < end; ++i) {
        offs[i]   = run;
        cursor[i] = run;
        run += counts[i];
    }
}

__global__ void fill_kernel(const int* __restrict__ src,
                            const int* __restrict__ tgt,
                            const float* __restrict__ ea,
                            int* __restrict__ cursor,
                            int* __restrict__ srcs,
                            float* __restrict__ wts) {
    int e = blockIdx.x * blockDim.x + threadIdx.x;
    if (e < N_EDGES) {
        int t   = tgt[e];
        int pos = atomicAdd(&cursor[t], 1);
        srcs[pos] = src[e];
        wts[pos]  = ea[e];
    }
}

// ---------------------------------------------------------------------------
// Aggregate: a[n] = h[n] + sum_{e in CSR[n]} h[src_e] * w_e
// One wave per node; lane j holds column j; coalesced 256B reads of h rows.
// ---------------------------------------------------------------------------
__global__ void aggregate_kernel(const float* __restrict__ h,
                                 const int* __restrict__ offs,
                                 const int* __restrict__ counts,
                                 const int* __restrict__ srcs,
                                 const float* __restrict__ wts,
                                 float* __restrict__ a) {
    const int lane = threadIdx.x & 63;
    const int node = (blockIdx.x * blockDim.x + threadIdx.x) >> 6;
    if (node >= N_NODES) return;

    const int beg = offs[node];
    const int cnt = counts[node];
    float acc = h[(size_t)node * HID + lane];
    for (int i = 0; i < cnt; ++i) {
        int   s = srcs[beg + i];   // wave-uniform
        float w = wts[beg + i];    // wave-uniform
        acc += h[(size_t)s * HID + lane] * w;
    }
    a[(size_t)node * HID + lane] = acc;
}

// ---------------------------------------------------------------------------
// Layer GEMM: hnext = relu(a @ W + b)   (100000x64 @ 64x64)
// ---------------------------------------------------------------------------
__global__ void gemm_hid_kernel(const float* __restrict__ a,
                                const float* __restrict__ W,
                                const float* __restrict__ b,
                                float* __restrict__ hnext) {
    __shared__ float sW[HID * HID];  // 16 KB
    for (int i = threadIdx.x; i < HID * HID; i += blockDim.x) sW[i] = W[i];
    __syncthreads();

    const int lane = threadIdx.x & 63;
    const int wave = threadIdx.x >> 6;
    const int row  = blockIdx.x * (blockDim.x >> 6) + wave;
    if (row >= N_NODES) return;

    const float4* ar4 = (const float4*)(a + (size_t)row * HID);
    float acc = b[lane];
    #pragma unroll
    for (int k4 = 0; k4 < HID / 4; ++k4) {
        float4 av = ar4[k4];
        acc += av.x * sW[(4 * k4 + 0) * HID + lane];
        acc += av.y * sW[(4 * k4 + 1) * HID + lane];
        acc += av.z * sW[(4 * k4 + 2) * HID + lane];
        acc += av.w * sW[(4 * k4 + 3) * HID + lane];
    }
    hnext[(size_t)row * HID + lane] = fmaxf(acc, 0.0f);
}

extern "C" void kernel_launch(void* const* d_in, const int* in_sizes, int n_in,
                              void* d_out, int out_size, void* d_ws, size_t ws_size,
                              hipStream_t stream) {
    const float* x   = (const float*)d_in[0];
    const int*   ei  = (const int*)  d_in[1];   // (2, E): [src | tgt]
    const float* ea  = (const float*)d_in[2];
    const float* Wi  = (const float*)d_in[3];
    const float* bi  = (const float*)d_in[4];
    const float* Wl[3] = { (const float*)d_in[5], (const float*)d_in[7], (const float*)d_in[9] };
    const float* bl[3] = { (const float*)d_in[6], (const float*)d_in[8], (const float*)d_in[10] };
    float* out = (float*)d_out;  // (4, N, HID)

    const int* src = ei;
    const int* tgt = ei + N_EDGES;

    // Workspace layout
    float* tmp    = (float*)d_ws;                    // N*HID floats (aggregate output)
    int*   counts = (int*)(tmp + (size_t)N_NODES * HID);
    int*   offs   = counts + N_NODES;
    int*   cursor = offs   + N_NODES;
    int*   srcs   = cursor + N_NODES;                // E ints
    float* wts    = (float*)(srcs + N_EDGES);        // E floats

    hipMemsetAsync(counts, 0, N_NODES * sizeof(int), stream);

    // CSR build
    hist_kernel<<<(N_EDGES + 255) / 256, 256, 0, stream>>>(tgt, counts);
    scan_kernel<<<1, 1024, 0, stream>>>(counts, offs, cursor);
    fill_kernel<<<(N_EDGES + 255) / 256, 256, 0, stream>>>(src, tgt, ea, cursor, srcs, wts);

    // h0 = relu(x @ Wi + bi) -> out slice 0
    const int rows_per_block = 4;  // 256 threads = 4 waves
    const int gemm_blocks = (N_NODES + rows_per_block - 1) / rows_per_block;
    gemm_in_kernel<<<gemm_blocks, 256, 0, stream>>>(x, Wi, bi, out);

    // 3 message-passing layers
    for (int l = 0; l < 3; ++l) {
        const float* h = out + (size_t)l * N_NODES * HID;
        float* hn      = out + (size_t)(l + 1) * N_NODES * HID;
        aggregate_kernel<<<(N_NODES + 3) / 4, 256, 0, stream>>>(h, offs, counts, srcs, wts, tmp);
        gemm_hid_kernel<<<gemm_blocks, 256, 0, stream>>>(tmp, Wl[l], bl[l], hn);
    }
}

// Round 2
// 1122.271 us; speedup vs baseline: 1.2884x; 1.2884x over previous
//
#include <hip/hip_runtime.h>
#include <hip/hip_bf16.h>

#define N_NODES 100000
#define N_EDGES 1600000
#define IN_DIM  128
#define HID     64
#define RPW     8   // rows per wave in GEMMs; 100000 % (4*RPW) == 0 -> 3125 blocks

// ---------------------------------------------------------------------------
// h0 = relu(x @ Wi + bi)   (100000x128 @ 128x64)
// 4 waves/block, 8 rows/wave: each sW LDS read feeds 8 FMAs.
// ---------------------------------------------------------------------------
__global__ void gemm_in_kernel(const float* __restrict__ x,
                               const float* __restrict__ Wi,
                               const float* __restrict__ bi,
                               float* __restrict__ h0) {
    __shared__ float sW[IN_DIM * HID];  // 32 KB
    for (int i = threadIdx.x; i < IN_DIM * HID; i += blockDim.x) sW[i] = Wi[i];
    __syncthreads();

    const int lane = threadIdx.x & 63;
    const int wave = threadIdx.x >> 6;
    const int row0 = (blockIdx.x * 4 + wave) * RPW;

    float b = bi[lane];
    float acc[RPW];
    #pragma unroll
    for (int r = 0; r < RPW; ++r) acc[r] = b;

    const float4* x4 = (const float4*)(x + (size_t)row0 * IN_DIM);
    for (int k4 = 0; k4 < IN_DIM / 4; ++k4) {
        float4 xv[RPW];
        #pragma unroll
        for (int r = 0; r < RPW; ++r) xv[r] = x4[r * (IN_DIM / 4) + k4];
        float w0 = sW[(4 * k4 + 0) * HID + lane];  // lanes consecutive: 2-way bank alias, free
        float w1 = sW[(4 * k4 + 1) * HID + lane];
        float w2 = sW[(4 * k4 + 2) * HID + lane];
        float w3 = sW[(4 * k4 + 3) * HID + lane];
        #pragma unroll
        for (int r = 0; r < RPW; ++r)
            acc[r] += xv[r].x * w0 + xv[r].y * w1 + xv[r].z * w2 + xv[r].w * w3;
    }
    #pragma unroll
    for (int r = 0; r < RPW; ++r)
        h0[(size_t)(row0 + r) * HID + lane] = fmaxf(acc[r], 0.0f);
}

// ---------------------------------------------------------------------------
// hnext = relu(a @ W + b)   (100000x64 @ 64x64), same structure
// ---------------------------------------------------------------------------
__global__ void gemm_hid_kernel(const float* __restrict__ a,
                                const float* __restrict__ W,
                                const float* __restrict__ b,
                                float* __restrict__ hnext) {
    __shared__ float sW[HID * HID];  // 16 KB
    for (int i = threadIdx.x; i < HID * HID; i += blockDim.x) sW[i] = W[i];
    __syncthreads();

    const int lane = threadIdx.x & 63;
    const int wave = threadIdx.x >> 6;
    const int row0 = (blockIdx.x * 4 + wave) * RPW;

    float bb = b[lane];
    float acc[RPW];
    #pragma unroll
    for (int r = 0; r < RPW; ++r) acc[r] = bb;

    const float4* a4 = (const float4*)(a + (size_t)row0 * HID);
    for (int k4 = 0; k4 < HID / 4; ++k4) {
        float4 av[RPW];
        #pragma unroll
        for (int r = 0; r < RPW; ++r) av[r] = a4[r * (HID / 4) + k4];
        float w0 = sW[(4 * k4 + 0) * HID + lane];
        float w1 = sW[(4 * k4 + 1) * HID + lane];
        float w2 = sW[(4 * k4 + 2) * HID + lane];
        float w3 = sW[(4 * k4 + 3) * HID + lane];
        #pragma unroll
        for (int r = 0; r < RPW; ++r)
            acc[r] += av[r].x * w0 + av[r].y * w1 + av[r].z * w2 + av[r].w * w3;
    }
    #pragma unroll
    for (int r = 0; r < RPW; ++r)
        hnext[(size_t)(row0 + r) * HID + lane] = fmaxf(acc[r], 0.0f);
}

// ---------------------------------------------------------------------------
// CSR build
// ---------------------------------------------------------------------------
__global__ void hist_kernel(const int* __restrict__ tgt, int* __restrict__ counts) {
    int e = blockIdx.x * blockDim.x + threadIdx.x;
    if (e < N_EDGES) atomicAdd(&counts[tgt[e]], 1);
}

__global__ void scan_kernel(const int* __restrict__ counts,
                            int* __restrict__ offs,
                            int* __restrict__ cursor) {
    __shared__ int partial[1024];
    const int T = 1024;
    const int tid = threadIdx.x;
    const int chunk = (N_NODES + T - 1) / T;  // 98
    const int start = tid * chunk;
    const int end   = min(start + chunk, N_NODES);

    int sum = 0;
    for (int i = start; i < end; ++i) sum += counts[i];
    partial[tid] = sum;
    __syncthreads();

    for (int off = 1; off < T; off <<= 1) {
        int v = (tid >= off) ? partial[tid - off] : 0;
        __syncthreads();
        partial[tid] += v;
        __syncthreads();
    }

    int run = partial[tid] - sum;  // exclusive base
    for (int i = start; i < end; ++i) {
        offs[i]   = run;
        cursor[i] = run;
        run += counts[i];
    }
}

__global__ void fill_kernel(const int* __restrict__ src,
                            const int* __restrict__ tgt,
                            const float* __restrict__ ea,
                            int* __restrict__ cursor,
                            int2* __restrict__ pairs) {
    int e = blockIdx.x * blockDim.x + threadIdx.x;
    if (e < N_EDGES) {
        int t   = tgt[e];
        int pos = atomicAdd(&cursor[t], 1);
        pairs[pos] = make_int2(src[e], __float_as_int(ea[e]));
    }
}

// ---------------------------------------------------------------------------
// a[n] = h[n] + sum_e h[src_e] * w_e.  One wave per node, lane = column.
// Unroll-8 with clamped tail: 8 independent gathers in flight per wave.
// ---------------------------------------------------------------------------
__global__ void aggregate_kernel(const float* __restrict__ h,
                                 const int* __restrict__ offs,
                                 const int* __restrict__ counts,
                                 const int2* __restrict__ pairs,
                                 float* __restrict__ a) {
    const int lane = threadIdx.x & 63;
    const int node = (blockIdx.x * blockDim.x + threadIdx.x) >> 6;
    if (node >= N_NODES) return;

    const int beg = offs[node];
    const int cnt = counts[node];
    float acc = h[(size_t)node * HID + lane];

    if (cnt > 0) {
        const int last = cnt - 1;
        for (int i = 0; i < cnt; i += 8) {
            int2 p[8];
            bool live[8];
            #pragma unroll
            for (int j = 0; j < 8; ++j) {
                int e = i + j;
                live[j] = (e <= last);
                p[j] = pairs[beg + (live[j] ? e : last)];
            }
            float v[8];
            #pragma unroll
            for (int j = 0; j < 8; ++j)
                v[j] = h[(size_t)p[j].x * HID + lane];
            #pragma unroll
            for (int j = 0; j < 8; ++j)
                acc += v[j] * (live[j] ? __int_as_float(p[j].y) : 0.0f);
        }
    }
    a[(size_t)node * HID + lane] = acc;
}

extern "C" void kernel_launch(void* const* d_in, const int* in_sizes, int n_in,
                              void* d_out, int out_size, void* d_ws, size_t ws_size,
                              hipStream_t stream) {
    const float* x   = (const float*)d_in[0];
    const int*   ei  = (const int*)  d_in[1];   // (2, E): [src | tgt]
    const float* ea  = (const float*)d_in[2];
    const float* Wi  = (const float*)d_in[3];
    const float* bi  = (const float*)d_in[4];
    const float* Wl[3] = { (const float*)d_in[5], (const float*)d_in[7], (const float*)d_in[9] };
    const float* bl[3] = { (const float*)d_in[6], (const float*)d_in[8], (const float*)d_in[10] };
    float* out = (float*)d_out;  // (4, N, HID)

    const int* src = ei;
    const int* tgt = ei + N_EDGES;

    // Workspace layout
    float* tmp    = (float*)d_ws;                    // N*HID floats
    int*   counts = (int*)(tmp + (size_t)N_NODES * HID);
    int*   offs   = counts + N_NODES;
    int*   cursor = offs   + N_NODES;
    int2*  pairs  = (int2*)(cursor + N_NODES);       // E * 8 bytes

    hipMemsetAsync(counts, 0, N_NODES * sizeof(int), stream);

    hist_kernel<<<(N_EDGES + 255) / 256, 256, 0, stream>>>(tgt, counts);
    scan_kernel<<<1, 1024, 0, stream>>>(counts, offs, cursor);
    fill_kernel<<<(N_EDGES + 255) / 256, 256, 0, stream>>>(src, tgt, ea, cursor, pairs);

    const int gemm_blocks = N_NODES / (4 * RPW);  // 3125
    gemm_in_kernel<<<gemm_blocks, 256, 0, stream>>>(x, Wi, bi, out);

    for (int l = 0; l < 3; ++l) {
        const float* h = out + (size_t)l * N_NODES * HID;
        float* hn      = out + (size_t)(l + 1) * N_NODES * HID;
        aggregate_kernel<<<(N_NODES + 3) / 4, 256, 0, stream>>>(h, offs, counts, pairs, tmp);
        gemm_hid_kernel<<<gemm_blocks, 256, 0, stream>>>(tmp, Wl[l], bl[l], hn);
    }
}

// Round 3
// 898.866 us; speedup vs baseline: 1.6086x; 1.2485x over previous
//
#include <hip/hip_runtime.h>
#include <hip/hip_bf16.h>

#define N_NODES 100000
#define N_EDGES 1600000
#define IN_DIM  128
#define HID     64
#define RPW     8          // rows per wave in GEMMs; 100000 % (4*RPW) == 0
#define SCAN_ELEMS 1024    // counts elements per scan block
#define SCAN_NB   ((N_NODES + SCAN_ELEMS - 1) / SCAN_ELEMS)   // 98

// ---------------------------------------------------------------------------
// h0 = relu(x @ Wi + bi)   (100000x128 @ 128x64)
// ---------------------------------------------------------------------------
__global__ void gemm_in_kernel(const float* __restrict__ x,
                               const float* __restrict__ Wi,
                               const float* __restrict__ bi,
                               float* __restrict__ h0) {
    __shared__ float sW[IN_DIM * HID];  // 32 KB
    for (int i = threadIdx.x; i < IN_DIM * HID; i += blockDim.x) sW[i] = Wi[i];
    __syncthreads();

    const int lane = threadIdx.x & 63;
    const int wave = threadIdx.x >> 6;
    const int row0 = (blockIdx.x * 4 + wave) * RPW;

    float b = bi[lane];
    float acc[RPW];
    #pragma unroll
    for (int r = 0; r < RPW; ++r) acc[r] = b;

    const float4* x4 = (const float4*)(x + (size_t)row0 * IN_DIM);
    for (int k4 = 0; k4 < IN_DIM / 4; ++k4) {
        float4 xv[RPW];
        #pragma unroll
        for (int r = 0; r < RPW; ++r) xv[r] = x4[r * (IN_DIM / 4) + k4];
        float w0 = sW[(4 * k4 + 0) * HID + lane];
        float w1 = sW[(4 * k4 + 1) * HID + lane];
        float w2 = sW[(4 * k4 + 2) * HID + lane];
        float w3 = sW[(4 * k4 + 3) * HID + lane];
        #pragma unroll
        for (int r = 0; r < RPW; ++r)
            acc[r] += xv[r].x * w0 + xv[r].y * w1 + xv[r].z * w2 + xv[r].w * w3;
    }
    #pragma unroll
    for (int r = 0; r < RPW; ++r)
        h0[(size_t)(row0 + r) * HID + lane] = fmaxf(acc[r], 0.0f);
}

// ---------------------------------------------------------------------------
// hnext = relu(a @ W + b)   (100000x64 @ 64x64)
// ---------------------------------------------------------------------------
__global__ void gemm_hid_kernel(const float* __restrict__ a,
                                const float* __restrict__ W,
                                const float* __restrict__ b,
                                float* __restrict__ hnext) {
    __shared__ float sW[HID * HID];  // 16 KB
    for (int i = threadIdx.x; i < HID * HID; i += blockDim.x) sW[i] = W[i];
    __syncthreads();

    const int lane = threadIdx.x & 63;
    const int wave = threadIdx.x >> 6;
    const int row0 = (blockIdx.x * 4 + wave) * RPW;

    float bb = b[lane];
    float acc[RPW];
    #pragma unroll
    for (int r = 0; r < RPW; ++r) acc[r] = bb;

    const float4* a4 = (const float4*)(a + (size_t)row0 * HID);
    for (int k4 = 0; k4 < HID / 4; ++k4) {
        float4 av[RPW];
        #pragma unroll
        for (int r = 0; r < RPW; ++r) av[r] = a4[r * (HID / 4) + k4];
        float w0 = sW[(4 * k4 + 0) * HID + lane];
        float w1 = sW[(4 * k4 + 1) * HID + lane];
        float w2 = sW[(4 * k4 + 2) * HID + lane];
        float w3 = sW[(4 * k4 + 3) * HID + lane];
        #pragma unroll
        for (int r = 0; r < RPW; ++r)
            acc[r] += av[r].x * w0 + av[r].y * w1 + av[r].z * w2 + av[r].w * w3;
    }
    #pragma unroll
    for (int r = 0; r < RPW; ++r)
        hnext[(size_t)(row0 + r) * HID + lane] = fmaxf(acc[r], 0.0f);
}

// ---------------------------------------------------------------------------
// CSR build: hist -> 3-dispatch device-wide exclusive scan -> fill
// ---------------------------------------------------------------------------
__global__ void hist_kernel(const int* __restrict__ tgt, int* __restrict__ counts) {
    int e = blockIdx.x * blockDim.x + threadIdx.x;
    if (e < N_EDGES) atomicAdd(&counts[tgt[e]], 1);
}

// 98 blocks x 256 threads: block b sums counts[b*1024 .. b*1024+1023] (coalesced)
__global__ void scan_reduce_kernel(const int* __restrict__ counts,
                                   int* __restrict__ blocksums) {
    __shared__ int wtot[4];
    const int tid  = threadIdx.x;
    const int lane = tid & 63;
    const int wid  = tid >> 6;
    const int base = blockIdx.x * SCAN_ELEMS;

    int sum = 0;
    for (int i = tid; i < SCAN_ELEMS; i += 256) {
        int idx = base + i;
        sum += (idx < N_NODES) ? counts[idx] : 0;
    }
    #pragma unroll
    for (int d = 1; d < 64; d <<= 1) sum += __shfl_xor(sum, d);
    if (lane == 0) wtot[wid] = sum;
    __syncthreads();
    if (tid == 0) blocksums[blockIdx.x] = wtot[0] + wtot[1] + wtot[2] + wtot[3];
}

// 1 block, 128 threads: exclusive scan of 98 block sums
__global__ void scan_base_kernel(const int* __restrict__ blocksums,
                                 int* __restrict__ blockbase) {
    __shared__ int s[128];
    const int tid = threadIdx.x;
    int v = (tid < SCAN_NB) ? blocksums[tid] : 0;
    s[tid] = v;
    __syncthreads();
    for (int off = 1; off < 128; off <<= 1) {
        int t = (tid >= off) ? s[tid - off] : 0;
        __syncthreads();
        s[tid] += t;
        __syncthreads();
    }
    if (tid < SCAN_NB) blockbase[tid] = s[tid] - v;
}

// 98 blocks x 256 threads x 4 elems: local scan + base, write offs & cursor
__global__ void scan_write_kernel(const int* __restrict__ counts,
                                  const int* __restrict__ blockbase,
                                  int* __restrict__ offs,
                                  int* __restrict__ cursor) {
    __shared__ int wtot[4];
    const int tid  = threadIdx.x;
    const int lane = tid & 63;
    const int wid  = tid >> 6;
    const int i0   = blockIdx.x * SCAN_ELEMS + tid * 4;

    int4 c;
    if (i0 + 3 < N_NODES) {
        c = *(const int4*)(counts + i0);
    } else {
        c.x = (i0 + 0 < N_NODES) ? counts[i0 + 0] : 0;
        c.y = (i0 + 1 < N_NODES) ? counts[i0 + 1] : 0;
        c.z = (i0 + 2 < N_NODES) ? counts[i0 + 2] : 0;
        c.w = (i0 + 3 < N_NODES) ? counts[i0 + 3] : 0;
    }
    int mysum = c.x + c.y + c.z + c.w;

    int sc = mysum;  // wave-inclusive scan
    #pragma unroll
    for (int d = 1; d < 64; d <<= 1) {
        int v = __shfl_up(sc, d);
        if (lane >= d) sc += v;
    }
    if (lane == 63) wtot[wid] = sc;
    __syncthreads();
    int wbase = 0;
    for (int w = 0; w < wid; ++w) wbase += wtot[w];

    int o0 = blockbase[blockIdx.x] + wbase + sc - mysum;
    int o1 = o0 + c.x, o2 = o1 + c.y, o3 = o2 + c.z;
    if (i0 + 3 < N_NODES) {
        *(int4*)(offs + i0)   = make_int4(o0, o1, o2, o3);
        *(int4*)(cursor + i0) = make_int4(o0, o1, o2, o3);
    } else {
        if (i0 + 0 < N_NODES) { offs[i0 + 0] = o0; cursor[i0 + 0] = o0; }
        if (i0 + 1 < N_NODES) { offs[i0 + 1] = o1; cursor[i0 + 1] = o1; }
        if (i0 + 2 < N_NODES) { offs[i0 + 2] = o2; cursor[i0 + 2] = o2; }
        if (i0 + 3 < N_NODES) { offs[i0 + 3] = o3; cursor[i0 + 3] = o3; }
    }
}

__global__ void fill_kernel(const int* __restrict__ src,
                            const int* __restrict__ tgt,
                            const float* __restrict__ ea,
                            int* __restrict__ cursor,
                            int2* __restrict__ pairs) {
    int e = blockIdx.x * blockDim.x + threadIdx.x;
    if (e < N_EDGES) {
        int t   = tgt[e];
        int pos = atomicAdd(&cursor[t], 1);
        pairs[pos] = make_int2(src[e], __float_as_int(ea[e]));
    }
}

// ---------------------------------------------------------------------------
// a[n] = h[n] + sum_e h[src_e] * w_e.  One wave per node, lane = column.
// ---------------------------------------------------------------------------
__global__ void aggregate_kernel(const float* __restrict__ h,
                                 const int* __restrict__ offs,
                                 const int* __restrict__ counts,
                                 const int2* __restrict__ pairs,
                                 float* __restrict__ a) {
    const int lane = threadIdx.x & 63;
    const int node = (blockIdx.x * blockDim.x + threadIdx.x) >> 6;
    if (node >= N_NODES) return;

    const int beg = offs[node];
    const int cnt = counts[node];
    float acc = h[(size_t)node * HID + lane];

    if (cnt > 0) {
        const int last = cnt - 1;
        for (int i = 0; i < cnt; i += 8) {
            int2 p[8];
            bool live[8];
            #pragma unroll
            for (int j = 0; j < 8; ++j) {
                int e = i + j;
                live[j] = (e <= last);
                p[j] = pairs[beg + (live[j] ? e : last)];
            }
            float v[8];
            #pragma unroll
            for (int j = 0; j < 8; ++j)
                v[j] = h[(size_t)p[j].x * HID + lane];
            #pragma unroll
            for (int j = 0; j < 8; ++j)
                acc += v[j] * (live[j] ? __int_as_float(p[j].y) : 0.0f);
        }
    }
    a[(size_t)node * HID + lane] = acc;
}

extern "C" void kernel_launch(void* const* d_in, const int* in_sizes, int n_in,
                              void* d_out, int out_size, void* d_ws, size_t ws_size,
                              hipStream_t stream) {
    const float* x   = (const float*)d_in[0];
    const int*   ei  = (const int*)  d_in[1];   // (2, E): [src | tgt]
    const float* ea  = (const float*)d_in[2];
    const float* Wi  = (const float*)d_in[3];
    const float* bi  = (const float*)d_in[4];
    const float* Wl[3] = { (const float*)d_in[5], (const float*)d_in[7], (const float*)d_in[9] };
    const float* bl[3] = { (const float*)d_in[6], (const float*)d_in[8], (const float*)d_in[10] };
    float* out = (float*)d_out;  // (4, N, HID)

    const int* src = ei;
    const int* tgt = ei + N_EDGES;

    // Workspace layout
    float* tmp       = (float*)d_ws;                    // N*HID floats
    int*   counts    = (int*)(tmp + (size_t)N_NODES * HID);
    int*   offs      = counts + N_NODES;
    int*   cursor    = offs   + N_NODES;
    int*   blocksums = cursor + N_NODES;                // SCAN_NB ints
    int*   blockbase = blocksums + 128;
    int2*  pairs     = (int2*)(blockbase + 128);        // E * 8 bytes (8B-aligned: offset even)

    hipMemsetAsync(counts, 0, N_NODES * sizeof(int), stream);

    hist_kernel<<<(N_EDGES + 255) / 256, 256, 0, stream>>>(tgt, counts);
    scan_reduce_kernel<<<SCAN_NB, 256, 0, stream>>>(counts, blocksums);
    scan_base_kernel<<<1, 128, 0, stream>>>(blocksums, blockbase);
    scan_write_kernel<<<SCAN_NB, 256, 0, stream>>>(counts, blockbase, offs, cursor);
    fill_kernel<<<(N_EDGES + 255) / 256, 256, 0, stream>>>(src, tgt, ea, cursor, pairs);

    const int gemm_blocks = N_NODES / (4 * RPW);  // 3125
    gemm_in_kernel<<<gemm_blocks, 256, 0, stream>>>(x, Wi, bi, out);

    for (int l = 0; l < 3; ++l) {
        const float* h = out + (size_t)l * N_NODES * HID;
        float* hn      = out + (size_t)(l + 1) * N_NODES * HID;
        aggregate_kernel<<<(N_NODES + 3) / 4, 256, 0, stream>>>(h, offs, counts, pairs, tmp);
        gemm_hid_kernel<<<gemm_blocks, 256, 0, stream>>>(tmp, Wl[l], bl[l], hn);
    }
}

// Round 4
// 678.317 us; speedup vs baseline: 2.1316x; 1.3251x over previous
//
#include <hip/hip_runtime.h>
#include <hip/hip_bf16.h>

#define N_NODES 100000
#define N_EDGES 1600000
#define IN_DIM  128
#define HID     64
#define RPW     8          // rows per wave; 4 waves * 8 = 32 rows/block
#define RPB     32         // rows per block
#define SCAN_ELEMS 1024
#define SCAN_NB   ((N_NODES + SCAN_ELEMS - 1) / SCAN_ELEMS)   // 98

// ---------------------------------------------------------------------------
// h0 = relu(x @ Wi + bi)   (100000x128 @ 128x64)
// x tile staged in LDS (coalesced float4), broadcast-read per row via b128.
// ---------------------------------------------------------------------------
__global__ void gemm_in_kernel(const float* __restrict__ x,
                               const float* __restrict__ Wi,
                               const float* __restrict__ bi,
                               float* __restrict__ h0) {
    __shared__ float sW[IN_DIM * HID];   // 32 KB
    __shared__ float sX[RPB * IN_DIM];   // 16 KB
    for (int i = threadIdx.x; i < IN_DIM * HID; i += 256) sW[i] = Wi[i];
    {
        const float4* xb4 = (const float4*)(x + (size_t)blockIdx.x * RPB * IN_DIM);
        float4* sX4 = (float4*)sX;
        #pragma unroll
        for (int i = 0; i < RPB * IN_DIM / 4 / 256; ++i)
            sX4[threadIdx.x + i * 256] = xb4[threadIdx.x + i * 256];
    }
    __syncthreads();

    const int lane = threadIdx.x & 63;
    const int wave = threadIdx.x >> 6;
    const int r0   = wave * RPW;              // row within block

    float b = bi[lane];
    float acc[RPW];
    #pragma unroll
    for (int r = 0; r < RPW; ++r) acc[r] = b;

    const float4* sX4 = (const float4*)sX;
    for (int k4 = 0; k4 < IN_DIM / 4; ++k4) {
        float4 xv[RPW];
        #pragma unroll
        for (int r = 0; r < RPW; ++r) xv[r] = sX4[(r0 + r) * (IN_DIM / 4) + k4];  // LDS broadcast
        float w0 = sW[(4 * k4 + 0) * HID + lane];
        float w1 = sW[(4 * k4 + 1) * HID + lane];
        float w2 = sW[(4 * k4 + 2) * HID + lane];
        float w3 = sW[(4 * k4 + 3) * HID + lane];
        #pragma unroll
        for (int r = 0; r < RPW; ++r)
            acc[r] += xv[r].x * w0 + xv[r].y * w1 + xv[r].z * w2 + xv[r].w * w3;
    }
    const int row0 = blockIdx.x * RPB + r0;
    #pragma unroll
    for (int r = 0; r < RPW; ++r)
        h0[(size_t)(row0 + r) * HID + lane] = fmaxf(acc[r], 0.0f);
}

// ---------------------------------------------------------------------------
// hnext = relu(a @ W + b)   (100000x64 @ 64x64), same structure
// ---------------------------------------------------------------------------
__global__ void gemm_hid_kernel(const float* __restrict__ a,
                                const float* __restrict__ W,
                                const float* __restrict__ b,
                                float* __restrict__ hnext) {
    __shared__ float sW[HID * HID];    // 16 KB
    __shared__ float sX[RPB * HID];    // 8 KB
    for (int i = threadIdx.x; i < HID * HID; i += 256) sW[i] = W[i];
    {
        const float4* ab4 = (const float4*)(a + (size_t)blockIdx.x * RPB * HID);
        float4* sX4 = (float4*)sX;
        #pragma unroll
        for (int i = 0; i < RPB * HID / 4 / 256; ++i)
            sX4[threadIdx.x + i * 256] = ab4[threadIdx.x + i * 256];
    }
    __syncthreads();

    const int lane = threadIdx.x & 63;
    const int wave = threadIdx.x >> 6;
    const int r0   = wave * RPW;

    float bb = b[lane];
    float acc[RPW];
    #pragma unroll
    for (int r = 0; r < RPW; ++r) acc[r] = bb;

    const float4* sX4 = (const float4*)sX;
    for (int k4 = 0; k4 < HID / 4; ++k4) {
        float4 av[RPW];
        #pragma unroll
        for (int r = 0; r < RPW; ++r) av[r] = sX4[(r0 + r) * (HID / 4) + k4];
        float w0 = sW[(4 * k4 + 0) * HID + lane];
        float w1 = sW[(4 * k4 + 1) * HID + lane];
        float w2 = sW[(4 * k4 + 2) * HID + lane];
        float w3 = sW[(4 * k4 + 3) * HID + lane];
        #pragma unroll
        for (int r = 0; r < RPW; ++r)
            acc[r] += av[r].x * w0 + av[r].y * w1 + av[r].z * w2 + av[r].w * w3;
    }
    const int row0 = blockIdx.x * RPB + r0;
    #pragma unroll
    for (int r = 0; r < RPW; ++r)
        hnext[(size_t)(row0 + r) * HID + lane] = fmaxf(acc[r], 0.0f);
}

// ---------------------------------------------------------------------------
// CSR build: hist -> 3-dispatch device-wide exclusive scan -> fill
// ---------------------------------------------------------------------------
__global__ void hist_kernel(const int* __restrict__ tgt, int* __restrict__ counts) {
    int e = blockIdx.x * blockDim.x + threadIdx.x;
    if (e < N_EDGES) atomicAdd(&counts[tgt[e]], 1);
}

__global__ void scan_reduce_kernel(const int* __restrict__ counts,
                                   int* __restrict__ blocksums) {
    __shared__ int wtot[4];
    const int tid  = threadIdx.x;
    const int lane = tid & 63;
    const int wid  = tid >> 6;
    const int base = blockIdx.x * SCAN_ELEMS;

    int sum = 0;
    for (int i = tid; i < SCAN_ELEMS; i += 256) {
        int idx = base + i;
        sum += (idx < N_NODES) ? counts[idx] : 0;
    }
    #pragma unroll
    for (int d = 1; d < 64; d <<= 1) sum += __shfl_xor(sum, d);
    if (lane == 0) wtot[wid] = sum;
    __syncthreads();
    if (tid == 0) blocksums[blockIdx.x] = wtot[0] + wtot[1] + wtot[2] + wtot[3];
}

__global__ void scan_base_kernel(const int* __restrict__ blocksums,
                                 int* __restrict__ blockbase) {
    __shared__ int s[128];
    const int tid = threadIdx.x;
    int v = (tid < SCAN_NB) ? blocksums[tid] : 0;
    s[tid] = v;
    __syncthreads();
    for (int off = 1; off < 128; off <<= 1) {
        int t = (tid >= off) ? s[tid - off] : 0;
        __syncthreads();
        s[tid] += t;
        __syncthreads();
    }
    if (tid < SCAN_NB) blockbase[tid] = s[tid] - v;
}

__global__ void scan_write_kernel(const int* __restrict__ counts,
                                  const int* __restrict__ blockbase,
                                  int* __restrict__ offs,
                                  int* __restrict__ cursor) {
    __shared__ int wtot[4];
    const int tid  = threadIdx.x;
    const int lane = tid & 63;
    const int wid  = tid >> 6;
    const int i0   = blockIdx.x * SCAN_ELEMS + tid * 4;

    int4 c;
    if (i0 + 3 < N_NODES) {
        c = *(const int4*)(counts + i0);
    } else {
        c.x = (i0 + 0 < N_NODES) ? counts[i0 + 0] : 0;
        c.y = (i0 + 1 < N_NODES) ? counts[i0 + 1] : 0;
        c.z = (i0 + 2 < N_NODES) ? counts[i0 + 2] : 0;
        c.w = (i0 + 3 < N_NODES) ? counts[i0 + 3] : 0;
    }
    int mysum = c.x + c.y + c.z + c.w;

    int sc = mysum;
    #pragma unroll
    for (int d = 1; d < 64; d <<= 1) {
        int v = __shfl_up(sc, d);
        if (lane >= d) sc += v;
    }
    if (lane == 63) wtot[wid] = sc;
    __syncthreads();
    int wbase = 0;
    for (int w = 0; w < wid; ++w) wbase += wtot[w];

    int o0 = blockbase[blockIdx.x] + wbase + sc - mysum;
    int o1 = o0 + c.x, o2 = o1 + c.y, o3 = o2 + c.z;
    if (i0 + 3 < N_NODES) {
        *(int4*)(offs + i0)   = make_int4(o0, o1, o2, o3);
        *(int4*)(cursor + i0) = make_int4(o0, o1, o2, o3);
    } else {
        if (i0 + 0 < N_NODES) { offs[i0 + 0] = o0; cursor[i0 + 0] = o0; }
        if (i0 + 1 < N_NODES) { offs[i0 + 1] = o1; cursor[i0 + 1] = o1; }
        if (i0 + 2 < N_NODES) { offs[i0 + 2] = o2; cursor[i0 + 2] = o2; }
        if (i0 + 3 < N_NODES) { offs[i0 + 3] = o3; cursor[i0 + 3] = o3; }
    }
}

__global__ void fill_kernel(const int* __restrict__ src,
                            const int* __restrict__ tgt,
                            const float* __restrict__ ea,
                            int* __restrict__ cursor,
                            int2* __restrict__ pairs) {
    int e = blockIdx.x * blockDim.x + threadIdx.x;
    if (e < N_EDGES) {
        int t   = tgt[e];
        int pos = atomicAdd(&cursor[t], 1);
        pairs[pos] = make_int2(src[e], __float_as_int(ea[e]));
    }
}

// ---------------------------------------------------------------------------
// a[n] = h[n] + sum_e h[src_e] * w_e.  One wave per node, lane = column.
// ---------------------------------------------------------------------------
__global__ void aggregate_kernel(const float* __restrict__ h,
                                 const int* __restrict__ offs,
                                 const int* __restrict__ counts,
                                 const int2* __restrict__ pairs,
                                 float* __restrict__ a) {
    const int lane = threadIdx.x & 63;
    const int node = (blockIdx.x * blockDim.x + threadIdx.x) >> 6;
    if (node >= N_NODES) return;

    const int beg = offs[node];
    const int cnt = counts[node];
    float acc = h[(size_t)node * HID + lane];

    if (cnt > 0) {
        const int last = cnt - 1;
        for (int i = 0; i < cnt; i += 8) {
            int2 p[8];
            bool live[8];
            #pragma unroll
            for (int j = 0; j < 8; ++j) {
                int e = i + j;
                live[j] = (e <= last);
                p[j] = pairs[beg + (live[j] ? e : last)];
            }
            float v[8];
            #pragma unroll
            for (int j = 0; j < 8; ++j)
                v[j] = h[(size_t)p[j].x * HID + lane];
            #pragma unroll
            for (int j = 0; j < 8; ++j)
                acc += v[j] * (live[j] ? __int_as_float(p[j].y) : 0.0f);
        }
    }
    a[(size_t)node * HID + lane] = acc;
}

extern "C" void kernel_launch(void* const* d_in, const int* in_sizes, int n_in,
                              void* d_out, int out_size, void* d_ws, size_t ws_size,
                              hipStream_t stream) {
    const float* x   = (const float*)d_in[0];
    const int*   ei  = (const int*)  d_in[1];   // (2, E): [src | tgt]
    const float* ea  = (const float*)d_in[2];
    const float* Wi  = (const float*)d_in[3];
    const float* bi  = (const float*)d_in[4];
    const float* Wl[3] = { (const float*)d_in[5], (const float*)d_in[7], (const float*)d_in[9] };
    const float* bl[3] = { (const float*)d_in[6], (const float*)d_in[8], (const float*)d_in[10] };
    float* out = (float*)d_out;  // (4, N, HID)

    const int* src = ei;
    const int* tgt = ei + N_EDGES;

    // Workspace layout
    float* tmp       = (float*)d_ws;                    // N*HID floats
    int*   counts    = (int*)(tmp + (size_t)N_NODES * HID);
    int*   offs      = counts + N_NODES;
    int*   cursor    = offs   + N_NODES;
    int*   blocksums = cursor + N_NODES;
    int*   blockbase = blocksums + 128;
    int2*  pairs     = (int2*)(blockbase + 128);        // E * 8 bytes

    hipMemsetAsync(counts, 0, N_NODES * sizeof(int), stream);

    hist_kernel<<<(N_EDGES + 255) / 256, 256, 0, stream>>>(tgt, counts);
    scan_reduce_kernel<<<SCAN_NB, 256, 0, stream>>>(counts, blocksums);
    scan_base_kernel<<<1, 128, 0, stream>>>(blocksums, blockbase);
    scan_write_kernel<<<SCAN_NB, 256, 0, stream>>>(counts, blockbase, offs, cursor);
    fill_kernel<<<(N_EDGES + 255) / 256, 256, 0, stream>>>(src, tgt, ea, cursor, pairs);

    const int gemm_blocks = N_NODES / RPB;  // 3125
    gemm_in_kernel<<<gemm_blocks, 256, 0, stream>>>(x, Wi, bi, out);

    for (int l = 0; l < 3; ++l) {
        const float* h = out + (size_t)l * N_NODES * HID;
        float* hn      = out + (size_t)(l + 1) * N_NODES * HID;
        aggregate_kernel<<<(N_NODES + 3) / 4, 256, 0, stream>>>(h, offs, counts, pairs, tmp);
        gemm_hid_kernel<<<gemm_blocks, 256, 0, stream>>>(tmp, Wl[l], bl[l], hn);
    }
}